// Round 6
// baseline (640.581 us; speedup 1.0000x reference)
//
#include <hip/hip_runtime.h>
#include <cstdint>

// SparseMLP: out = relu(relu(x@W1^T+b1)@W2^T+b2)@W3^T+b3
// M = N = K = 4096 per layer. fp32 in/out; fp16 MFMA internally.
//
// R10 vs R9 (577us; GEMM 126.5 == R4/R6/R7 within 5%):
// Model fit across R4-R9: serial LDS(2300cyc) + MFMA(2484cyc) = 4784 ~=
// measured 4745 cyc/K-tile. Barrier-locked waves never overlap the pipes.
// Fix = cut LDS traffic + de-lockstep:
//  - A OPERAND IN REGISTERS: blocked layout makes each A-frag a contiguous
//    1KB line -> per-wave global_load_dwordx4 direct to VGPR (lane*16,
//    coalesced), prefetched 1 tile ahead in the phases with no LDS reads.
//    A never touches LDS. A-traffic 1.05GB/GEMM on the VMEM/L2 pipe
//    (A panel is L3-resident), parallel to the LDS pipe.
//  - B-only LDS: 64KB total (2 buf x 32KB), stage 32KB + read 128KB per
//    tile = 2.6GB/GEMM (was 4.19).
//  - ONE barrier per K-tile (B cross-wave coherence only) -> waves drift
//    across the 4 phases, LDS bursts of one wave overlap MFMA of another.
//  - vmcnt ledger (audited; issue order/tile: G2(P0) aA4(postP1) G2(P2)
//    aB4(postP3); invariant at tile start: {aB(T)4} in flight):
//      pre-P0  vmcnt(6): no-op steady, retires aA0 at T=0
//      pre-P2  vmcnt(6): retires aB(T) (vmcnt(0) at T=NT-1)
//      tile-end vmcnt(4): retires G2a+aA(T+1)+G2b, keeps aB(T+1) in flight
//  - wave grid 4m x 2n (wave-tile 64x128), acc[4][8], b[8] reused across
//    ks-phases, aA[4]/aB[4] ping-pong: ~210 VGPR, no spill at 2 w/SIMD.
//  - cvt rewritten wave-per-unit: in-reads 128B segments (R9 was 16B
//    lane-scattered -> ~130us hidden cost), out contiguous 1KB/wave.

#define MATN 4096
#define NT (MATN / 64)  // 64 K-tiles

typedef _Float16 half8 __attribute__((ext_vector_type(8)));
typedef float f32x4 __attribute__((ext_vector_type(4)));

// async global->LDS, 16B/lane. LDS dest = wave-uniform base + lane*16.
__device__ __forceinline__ void glds16(const void* g, void* l) {
    __builtin_amdgcn_global_load_lds(
        (const __attribute__((address_space(1))) char*)(uintptr_t)g,
        (__attribute__((address_space(3))) char*)(uintptr_t)l,
        16, 0, 0);
}

// fp32 row-major -> blocked f16. One unit u = (R,T,ks) = 1KB out chunk:
// lane (kq=l>>4, r16=l&15) reads 8 floats at in[(R*16+r16)*4096 + T*64 +
// ks*32 + kq*8] (16 rows x 128B segments) -> out[u*512 + lane*8].
__device__ __forceinline__ void cvtblk_body(const float* __restrict__ in,
                                            _Float16* __restrict__ out,
                                            int nunits) {
    const int lane = threadIdx.x & 63;
    const int r16 = lane & 15, kq = lane >> 4;
    const int wv = (blockIdx.x * 256 + (int)threadIdx.x) >> 6;
    const int nw = (gridDim.x * 256) >> 6;
    for (int u = wv; u < nunits; u += nw) {
        const int ks = u & 1, T = (u >> 1) & 63, R = u >> 7;
        const float* p =
            in + (size_t)(R * 16 + r16) * MATN + T * 64 + ks * 32 + kq * 8;
        float4 a = *(const float4*)p;
        float4 b = *(const float4*)(p + 4);
        half8 o;
        o[0] = (_Float16)a.x; o[1] = (_Float16)a.y;
        o[2] = (_Float16)a.z; o[3] = (_Float16)a.w;
        o[4] = (_Float16)b.x; o[5] = (_Float16)b.y;
        o[6] = (_Float16)b.z; o[7] = (_Float16)b.w;
        *(half8*)(out + (size_t)u * 512 + lane * 8) = o;
    }
}

__global__ __launch_bounds__(256)
void cvt_blk(const float* __restrict__ in, _Float16* __restrict__ out, int nu) {
    cvtblk_body(in, out, nu);
}

__global__ __launch_bounds__(256)
void cvt_blk2(const float* __restrict__ i0, _Float16* __restrict__ o0,
              const float* __restrict__ i1, _Float16* __restrict__ o1, int nu) {
    cvtblk_body(blockIdx.y ? i1 : i0, blockIdx.y ? o1 : o0, nu);
}

__global__ __launch_bounds__(256)
void cvt_blk4(const float* __restrict__ i0, _Float16* __restrict__ o0,
              const float* __restrict__ i1, _Float16* __restrict__ o1,
              const float* __restrict__ i2, _Float16* __restrict__ o2,
              const float* __restrict__ i3, _Float16* __restrict__ o3, int nu) {
    const float* in;
    _Float16* out;
    switch (blockIdx.y) {
        case 0: in = i0; out = o0; break;
        case 1: in = i1; out = o1; break;
        case 2: in = i2; out = o2; break;
        default: in = i3; out = o3; break;
    }
    cvtblk_body(in, out, nu);
}

// C[m][n] = sum_k A[m][k]*B[n][k] + bias[n] (optional ReLU).
// A,B blocked-f16: chunk (R,T,ks) at byte R*131072 + T*2048 + ks*1024 holds
// rows R*16..+16, cols T*64+ks*32..+32; within: [kq][r16][16B].
// 256x256 tile, BK=64, 8 waves (4M x 2N), per-wave 64x128, acc[4][8].
#define MFMA_(d, x, y) d = __builtin_amdgcn_mfma_f32_16x16x32_f16(x, y, d, 0, 0, 0)

template <bool RELU, bool OBLK, typename OutT>
__global__ __launch_bounds__(512, 2)
void gemm_areg(const _Float16* __restrict__ A, const _Float16* __restrict__ B,
               const float* __restrict__ bias, OutT* __restrict__ C) {
    // B-only LDS: [buf 2][nj 0..15][ks 0..1][1KB]. 64 KB.
    __shared__ _Float16 ldsB[2][16384];

    const int tid  = threadIdx.x;
    const int lane = tid & 63;
    const int w    = tid >> 6;   // 8 waves
    const int wm   = w >> 1;     // 0..3: rows wm*64..+64
    const int wn   = w & 1;      // 0..1: cols wn*128..+128
    const int l16  = lane & 15;
    const int kq   = lane >> 4;

    // bijective XCD swizzle: 256 blocks, 256 % 8 == 0
    const int bid   = blockIdx.y * 16 + blockIdx.x;
    const int sbid  = (bid & 7) * 32 + (bid >> 3);
    const int tileM = (sbid >> 4) * 256;
    const int tileN = (sbid & 15) * 256;

    char* const ldsb = (char*)ldsB;
    const int lb = lane * 16;

    // B staging: unit (g,j): wave w copies frag nj=g*8+w, ks=j (1KB).
    const char* const bSrc =
        (const char*)B + (size_t)((tileN >> 4) + w) * 131072 + lb;
#define SB(Tt, g, j)                                                           \
    do {                                                                       \
        if ((Tt) < NT)                                                         \
            glds16(bSrc + (size_t)(g)*1048576 + (size_t)(Tt)*2048 + (j)*1024,  \
                   ldsb + ((Tt)&1) * 32768 + ((g)*8 + w) * 2048 + (j)*1024);   \
    } while (0)

    // A direct-to-reg: wave wm owns frags R = tileM/16 + wm*4 + i.
    const char* const aSrc =
        (const char*)A + (size_t)((tileM >> 4) + wm * 4) * 131072 + lb;
#define LA(dst, Tt, ks_)                                                       \
    do {                                                                       \
        if ((Tt) < NT) {                                                       \
            _Pragma("unroll") for (int i_ = 0; i_ < 4; ++i_) dst[i_] =         \
                *(const half8*)(aSrc + (size_t)i_ * 131072 +                   \
                                (size_t)(Tt)*2048 + (ks_)*1024);               \
        }                                                                      \
    } while (0)

    half8 aA[4], aB[4], b[8];
    f32x4 acc[4][8] = {};

    // prologue: B(0) 4 units + aA(0) + aB(0) = 12 in flight; vmcnt(8)
    // retires the B glds, leaves the 8 A-loads.
    SB(0, 0, 0); SB(0, 1, 0); SB(0, 0, 1); SB(0, 1, 1);
    LA(aA, 0, 0);
    LA(aB, 0, 1);
    asm volatile("s_waitcnt vmcnt(8)" ::: "memory");
    __builtin_amdgcn_s_barrier();

#pragma unroll 2
    for (int T = 0; T < NT; ++T) {
        const char* Brd = ldsb + (T & 1) * 32768 + wn * 16384 + lb;

        // ---- P0: ks0, n0..3 ----
#pragma unroll
        for (int n = 0; n < 4; ++n) b[n] = *(const half8*)(Brd + n * 2048);
        SB(T + 1, 0, 0); SB(T + 1, 1, 0);
        asm volatile("s_waitcnt vmcnt(6)" ::: "memory");  // aA(T) @T=0; nop steady
        asm volatile("s_waitcnt lgkmcnt(0)" ::: "memory");
        __builtin_amdgcn_sched_barrier(0);
        __builtin_amdgcn_s_setprio(1);
#pragma unroll
        for (int i = 0; i < 4; ++i)
#pragma unroll
            for (int n = 0; n < 4; ++n) MFMA_(acc[i][n], aA[i], b[n]);
        __builtin_amdgcn_s_setprio(0);

        // ---- P1: ks0, n4..7 ----
#pragma unroll
        for (int n = 0; n < 4; ++n)
            b[4 + n] = *(const half8*)(Brd + (4 + n) * 2048);
        asm volatile("s_waitcnt lgkmcnt(0)" ::: "memory");
        __builtin_amdgcn_sched_barrier(0);
        __builtin_amdgcn_s_setprio(1);
#pragma unroll
        for (int i = 0; i < 4; ++i)
#pragma unroll
            for (int n = 0; n < 4; ++n) MFMA_(acc[i][4 + n], aA[i], b[4 + n]);
        __builtin_amdgcn_s_setprio(0);
        LA(aA, T + 1, 0);  // prefetch A ks0 of next tile (aA dead)

        // retire aB(T) before P2 consumes it
        if (T < NT - 1)
            asm volatile("s_waitcnt vmcnt(6)" ::: "memory");
        else
            asm volatile("s_waitcnt vmcnt(0)" ::: "memory");

        // ---- P2: ks1, n4..7 ----
#pragma unroll
        for (int n = 0; n < 4; ++n)
            b[4 + n] = *(const half8*)(Brd + (4 + n) * 2048 + 1024);
        SB(T + 1, 0, 1); SB(T + 1, 1, 1);
        asm volatile("s_waitcnt lgkmcnt(0)" ::: "memory");
        __builtin_amdgcn_sched_barrier(0);
        __builtin_amdgcn_s_setprio(1);
#pragma unroll
        for (int i = 0; i < 4; ++i)
#pragma unroll
            for (int n = 0; n < 4; ++n) MFMA_(acc[i][4 + n], aB[i], b[4 + n]);
        __builtin_amdgcn_s_setprio(0);

        // ---- P3: ks1, n0..3 ----
#pragma unroll
        for (int n = 0; n < 4; ++n)
            b[n] = *(const half8*)(Brd + n * 2048 + 1024);
        asm volatile("s_waitcnt lgkmcnt(0)" ::: "memory");
        __builtin_amdgcn_sched_barrier(0);
        __builtin_amdgcn_s_setprio(1);
#pragma unroll
        for (int i = 0; i < 4; ++i)
#pragma unroll
            for (int n = 0; n < 4; ++n) MFMA_(acc[i][n], aB[i], b[n]);
        __builtin_amdgcn_s_setprio(0);
        LA(aB, T + 1, 1);  // prefetch A ks1 of next tile (aB dead)

        // tile-end: retire G2a + aA(T+1) + G2b (B cross-wave visibility +
        // aA ready for T+1 P0); keep aB(T+1) in flight across the barrier.
        if (T < NT - 1)
            asm volatile("s_waitcnt vmcnt(4)" ::: "memory");
        else
            asm volatile("s_waitcnt vmcnt(0)" ::: "memory");
        __builtin_amdgcn_s_barrier();
    }
#undef SB
#undef LA

    // epilogue: C/D layout col = lane&15, row = (lane>>4)*4 + reg (m89).
    // acc[i][n] <-> rows tileM + wm*64 + i*16, cols tileN + wn*128 + n*16.
    if (OBLK) {
        char* const Cb = (char*)C;
#pragma unroll
        for (int n = 0; n < 8; ++n) {
            const int cw = n * 16 + l16;  // col within wave's 128
            const int gn = tileN + wn * 128 + cw;
            const float bv = bias[gn];
            const size_t colOff = (size_t)((tileN >> 6) + wn * 2 + (n >> 2)) * 2048 +
                                  ((n >> 1) & 1) * 1024 + (n & 1) * 512 +
                                  (l16 >> 3) * 256 + (l16 & 7) * 2;
#pragma unroll
            for (int i = 0; i < 4; ++i) {
                const size_t Roff =
                    (size_t)((tileM >> 4) + wm * 4 + i) * 131072;
#pragma unroll
                for (int r = 0; r < 4; ++r) {
                    float v = acc[i][n][r] + bv;
                    if (RELU) v = v > 0.f ? v : 0.f;
                    *(_Float16*)(Cb + Roff + colOff + (kq * 4 + r) * 16) =
                        (_Float16)v;
                }
            }
        }
    } else {
#pragma unroll
        for (int n = 0; n < 8; ++n) {
            const int gn = tileN + wn * 128 + n * 16 + l16;
            const float bv = bias[gn];
#pragma unroll
            for (int i = 0; i < 4; ++i) {
                const int gm = tileM + wm * 64 + i * 16 + kq * 4;
#pragma unroll
                for (int r = 0; r < 4; ++r) {
                    float v = acc[i][n][r] + bv;
                    if (RELU) v = v > 0.f ? v : 0.f;
                    C[(size_t)(gm + r) * MATN + gn] = (OutT)v;
                }
            }
        }
    }
}

extern "C" void kernel_launch(void* const* d_in, const int* in_sizes, int n_in,
                              void* d_out, int out_size, void* d_ws, size_t ws_size,
                              hipStream_t stream) {
    const float* x  = (const float*)d_in[0];
    const float* W1 = (const float*)d_in[1];
    const float* b1 = (const float*)d_in[2];
    const float* W2 = (const float*)d_in[3];
    const float* b2 = (const float*)d_in[4];
    const float* W3 = (const float*)d_in[5];
    const float* b3 = (const float*)d_in[6];
    float* out = (float*)d_out;

    const size_t MAT = (size_t)MATN * MATN;
    const size_t HB  = MAT * 2;  // bytes per f16 matrix
    const int nu = (int)(MAT / 512);  // 32768 units per matrix
    dim3 ggrid(MATN / 256, MATN / 256);  // 16x16

    if (ws_size >= HB * 5) {
        _Float16* xb = (_Float16*)d_ws;
        _Float16* w1 = (_Float16*)((char*)d_ws + HB);
        _Float16* w2 = (_Float16*)((char*)d_ws + HB * 2);
        _Float16* w3 = (_Float16*)((char*)d_ws + HB * 3);
        _Float16* h1 = (_Float16*)((char*)d_ws + HB * 4);
        _Float16* h2 = xb;  // xb dead after layer 1

        cvt_blk4<<<dim3(2048, 4), 256, 0, stream>>>(x, xb, W1, w1, W2, w2,
                                                    W3, w3, nu);
        gemm_areg<true, true, _Float16><<<ggrid, 512, 0, stream>>>(xb, w1, b1, h1);
        gemm_areg<true, true, _Float16><<<ggrid, 512, 0, stream>>>(h1, w2, b2, h2);
        gemm_areg<false, false, float><<<ggrid, 512, 0, stream>>>(h2, w3, b3, out);
    } else {
        _Float16* xb = (_Float16*)d_ws;
        _Float16* wb = (_Float16*)((char*)d_ws + HB);
        _Float16* h1 = (_Float16*)((char*)d_ws + HB * 2);
        _Float16* h2 = xb;

        cvt_blk2<<<dim3(2048, 2), 256, 0, stream>>>(x, xb, W1, wb, nu);
        gemm_areg<true, true, _Float16><<<ggrid, 512, 0, stream>>>(xb, wb, b1, h1);
        cvt_blk<<<2048, 256, 0, stream>>>(W2, wb, nu);
        gemm_areg<true, true, _Float16><<<ggrid, 512, 0, stream>>>(h1, wb, b2, h2);
        cvt_blk<<<2048, 256, 0, stream>>>(W3, wb, nu);
        gemm_areg<false, false, float><<<ggrid, 512, 0, stream>>>(h2, wb, b3, out);
    }
}